// Round 5
// baseline (137.714 us; speedup 1.0000x reference)
//
#include <hip/hip_runtime.h>
#include <stdint.h>

// N=65536 points, M=1024 gaussians, D=2, C=3, K=10
#define MG 1024
#define KTOP 10
#define EPSF 1e-6f
#define GRID_C 32
#define NBINS (GRID_C * GRID_C)   // 1024 cells -> ~64 pts/cell = one wave/cell

typedef unsigned long long u64;

__device__ __forceinline__ int cell_of(float x0, float x1) {
    int ix = (int)(x0 * GRID_C); ix = ix < 0 ? 0 : (ix > GRID_C - 1 ? GRID_C - 1 : ix);
    int iy = (int)(x1 * GRID_C); iy = iy < 0 ? 0 : (iy > GRID_C - 1 ? GRID_C - 1 : iy);
    return iy * GRID_C + ix;
}

__global__ __launch_bounds__(256) void k_hist(const float* __restrict__ x,
                                              uint32_t* __restrict__ hist, int N) {
    const int n = blockIdx.x * 256 + threadIdx.x;
    if (n < N) atomicAdd(&hist[cell_of(x[2 * n], x[2 * n + 1])], 1u);
}

// 1024-bin exclusive scan with one 256-thread block: 4 bins/thread serial + 8-step LDS scan.
__global__ __launch_bounds__(256) void k_scan(const uint32_t* __restrict__ hist,
                                              uint32_t* __restrict__ cursor) {
    __shared__ uint32_t s[256];
    const int t = threadIdx.x;
    const uint32_t v0 = hist[4 * t], v1 = hist[4 * t + 1], v2 = hist[4 * t + 2], v3 = hist[4 * t + 3];
    const uint32_t p1 = v0, p2 = v0 + v1, p3 = p2 + v2, sum = p3 + v3;
    s[t] = sum;
    __syncthreads();
    #pragma unroll
    for (int o = 1; o < 256; o <<= 1) {
        const uint32_t add = (t >= o) ? s[t - o] : 0u;
        __syncthreads();
        s[t] += add;
        __syncthreads();
    }
    const uint32_t excl = s[t] - sum;
    cursor[4 * t]     = excl;
    cursor[4 * t + 1] = excl + p1;
    cursor[4 * t + 2] = excl + p2;
    cursor[4 * t + 3] = excl + p3;
}

__global__ __launch_bounds__(256) void k_scatter(const float* __restrict__ x,
                                                 uint32_t* __restrict__ cursor,
                                                 uint32_t* __restrict__ perm, int N) {
    const int n = blockIdx.x * 256 + threadIdx.x;
    if (n < N) {
        const uint32_t r = atomicAdd(&cursor[cell_of(x[2 * n], x[2 * n + 1])], 1u);
        perm[r] = (uint32_t)n;
    }
}

// Main: block = 64 points x 4 slices (waves). Wave's 64 lanes = one spatial cell
// (via perm) -> screened insert's wave-any prob collapses after warmup.
// Selection bit-exact: u64 key network; float screen uses >= so exact-value ties
// (index tie-break) still enter the network. Grid 1024 = 4 blocks/CU resident
// (LDS 36KB) -> 16 waves/CU, fixing R4's 2-blocks/CU + tail imbalance.
__global__ __launch_bounds__(256, 4) void k_main(
    const float* __restrict__ x, const float* __restrict__ mus,
    const float* __restrict__ covs, const float* __restrict__ cols,
    const uint32_t* __restrict__ perm, float* __restrict__ out, int N)
{
    __shared__ float4 garr[MG];                       // mux, muy, A, B  (16 KB)
    __shared__ __align__(16) float garrC[MG];         // C               (4 KB)
    __shared__ float4 gcol[MG];                       // r, g, b, -      (16 KB)
    u64* mbuf = (u64*)garr;   // publish buffer aliases garr after the gaussian loop (15360 B)

    const int t = threadIdx.x;
    #pragma unroll
    for (int k = 0; k < MG / 256; ++k) {
        const int m = t + 256 * k;
        const float4 cv = ((const float4*)covs)[m];
        const float2 mu = ((const float2*)mus)[m];
        const float inv = 1.0f / (cv.x * cv.w - cv.y * cv.z);
        garr[m]  = make_float4(mu.x, mu.y, -0.5f * cv.w * inv, cv.y * inv);
        garrC[m] = -0.5f * cv.x * inv;
        gcol[m]  = make_float4(cols[m * 3], cols[m * 3 + 1], cols[m * 3 + 2], 0.0f);
    }
    __syncthreads();

    const int lane = t & 63, sl = t >> 6;
    int idx = blockIdx.x * 64 + lane;
    const bool valid = (idx < N);
    if (!valid) idx = N - 1;
    const int p = perm ? (int)perm[idx] : idx;
    const float2 xv = ((const float2*)x)[p];
    const float x0 = xv.x, x1 = xv.y;

    u64 topk[KTOP];
    const u64 SENT = ((u64)0x007FFFFFull) << 10;   // packed -inf, index 1023
    #pragma unroll
    for (int j = 0; j < KTOP; ++j) topk[j] = SENT;
    float thr = __uint_as_float(0xff800000u);      // -inf: warmup always passes screen

    auto net_insert = [&](u64 key) {
        bool c[KTOP];
        #pragma unroll
        for (int j = 0; j < KTOP; ++j) c[j] = topk[j] >= key;
        #pragma unroll
        for (int j = KTOP - 1; j >= 1; --j)
            topk[j] = c[j] ? topk[j] : (c[j - 1] ? key : topk[j - 1]);
        topk[0] = c[0] ? topk[0] : key;
    };
    auto ins = [&](float q, int m) {
        if (__any(q >= thr)) {
            const uint32_t b = __float_as_uint(q);
            const uint32_t msk = (uint32_t)((int32_t)b >> 31) | 0x80000000u;
            net_insert(((u64)(b ^ msk) << 10) | (u64)(MG - 1 - m));
            const uint32_t kb = (uint32_t)(topk[KTOP - 1] >> 10);
            const uint32_t bb = ((int32_t)kb < 0) ? (kb ^ 0x80000000u) : ~kb;
            thr = __uint_as_float(bb);             // value of current 10th
        }
    };

    const int mbase = sl * (MG / 4);
    for (int i = 0; i < MG / 4; i += 4) {
        const int m = mbase + i;
        const float4 p0 = garr[m], p1 = garr[m + 1], p2 = garr[m + 2], p3 = garr[m + 3];
        const float4 c4 = *(const float4*)&garrC[m];
        const float dx0 = x0 - p0.x, dy0 = x1 - p0.y;
        const float dx1 = x0 - p1.x, dy1 = x1 - p1.y;
        const float dx2 = x0 - p2.x, dy2 = x1 - p2.y;
        const float dx3 = x0 - p3.x, dy3 = x1 - p3.y;
        const float q0 = fmaf(fmaf(p0.z, dx0, p0.w * dy0), dx0, c4.x * (dy0 * dy0));
        const float q1 = fmaf(fmaf(p1.z, dx1, p1.w * dy1), dx1, c4.y * (dy1 * dy1));
        const float q2 = fmaf(fmaf(p2.z, dx2, p2.w * dy2), dx2, c4.z * (dy2 * dy2));
        const float q3 = fmaf(fmaf(p3.z, dx3, p3.w * dy3), dx3, c4.w * (dy3 * dy3));
        const float qm = fmaxf(fmaxf(q0, q1), fmaxf(q2, q3));
        if (__any(qm >= thr)) {
            ins(q0, m); ins(q1, m + 1); ins(q2, m + 2); ins(q3, m + 3);
        }
    }

    __syncthreads();                      // all waves done reading garr; mbuf aliases it now

    if (sl != 0) {
        #pragma unroll
        for (int j = 0; j < KTOP; ++j)
            mbuf[((sl - 1) * KTOP + j) * 64 + lane] = topk[j];
    }
    __syncthreads();

    if (sl == 0) {
        #pragma unroll 1
        for (int r = 0; r < 3 * KTOP; ++r) {
            const u64 key = mbuf[r * 64 + lane];
            if (__any(key > topk[KTOP - 1])) net_insert(key);
        }
        float vsum = 0.0f, rc = 0.0f, gc = 0.0f, bc = 0.0f;
        #pragma unroll
        for (int j = 0; j < KTOP; ++j) {
            const u64 key = topk[j];
            const int m = (MG - 1) - (int)(key & 1023u);
            const uint32_t kb = (uint32_t)(key >> 10);
            const uint32_t b = ((int32_t)kb < 0) ? (kb ^ 0x80000000u) : ~kb;
            const float v = __expf(__uint_as_float(b));
            const float4 cl = gcol[m];
            vsum += v;
            rc = fmaf(v, cl.x, rc);
            gc = fmaf(v, cl.y, gc);
            bc = fmaf(v, cl.z, bc);
        }
        const float s = 1.0f / (vsum + EPSF);
        if (valid) {
            out[p * 3 + 0] = rc * s;
            out[p * 3 + 1] = gc * s;
            out[p * 3 + 2] = bc * s;
        }
    }
}

extern "C" void kernel_launch(void* const* d_in, const int* in_sizes, int n_in,
                              void* d_out, int out_size, void* d_ws, size_t ws_size,
                              hipStream_t stream) {
    const float* x    = (const float*)d_in[0];
    const float* mus  = (const float*)d_in[1];
    const float* covs = (const float*)d_in[2];
    const float* cols = (const float*)d_in[3];
    float* out = (float*)d_out;
    const int N = in_sizes[0] / 2;

    uint32_t* hist   = (uint32_t*)d_ws;
    uint32_t* cursor = hist + NBINS;
    uint32_t* perm   = cursor + NBINS;
    const size_t need = (size_t)(2 * NBINS + N) * sizeof(uint32_t);
    const bool use_sort = (ws_size >= need);

    if (use_sort) {
        hipMemsetAsync(hist, 0, NBINS * sizeof(uint32_t), stream);
        k_hist<<<(N + 255) / 256, 256, 0, stream>>>(x, hist, N);
        k_scan<<<1, 256, 0, stream>>>(hist, cursor);
        k_scatter<<<(N + 255) / 256, 256, 0, stream>>>(x, cursor, perm, N);
    }
    k_main<<<(N + 63) / 64, 256, 0, stream>>>(x, mus, covs, cols,
                                              use_sort ? perm : (const uint32_t*)nullptr,
                                              out, N);
}